// Round 5
// baseline (53.697 us; speedup 1.0000x reference)
//
#include <hip/hip_runtime.h>
#include <hip/hip_bf16.h>

typedef __attribute__((ext_vector_type(8))) short bf16x8;
typedef __attribute__((ext_vector_type(16))) float f32x16;
typedef __attribute__((ext_vector_type(4))) unsigned int u32x4;

#define CC 128
#define KK 128
#define HH 56
#define WW 56
#define HW (HH * WW)
#define PH_STRIDE 38400  // [6 rows][40 cols][8 slots][16B]

__device__ __forceinline__ unsigned short f2bf(float f) {
  unsigned int u = __builtin_bit_cast(unsigned int, f);
  u += 0x7FFFu + ((u >> 16) & 1u);
  return (unsigned short)(u >> 16);
}

__device__ __forceinline__ f32x16 mfma32(bf16x8 a, bf16x8 b, f32x16 c) {
  return __builtin_amdgcn_mfma_f32_32x32x16_bf16(a, b, c, 0, 0, 0);
}

// K1: kernel (K,C,3,3) f32 -> wt4 bf16, element index:
//   e = (((ph*9+rs)*4+cs)*4 + kp*2+kfl)*512 + lane*8 + j
//   k = kp*64+kfl*32+(lane&31) ; c = ph*64+cs*16+(lane>>5)*8+j
__global__ void wtrans_kernel(const float* __restrict__ kin,
                              unsigned short* __restrict__ wt4) {
  int e = blockIdx.x * 256 + threadIdx.x;  // 147456 exact
  int j = e & 7;
  int l = (e >> 3) & 63;
  int q = e >> 9;  // 0..287
  int kfl = q & 1;
  int kp = (q >> 1) & 1;
  int cs = (q >> 2) & 3;
  int g = q >> 4;  // 0..17
  int ph = g / 9;
  int rs = g - ph * 9;
  int k = kp * 64 + kfl * 32 + (l & 31);
  int c = ph * 64 + cs * 16 + (l >> 5) * 8 + j;
  wt4[e] = f2bf(kin[(k * CC + c) * 9 + rs]);
}

// K2: 3x3 conv, implicit GEMM, mfma_f32_32x32x16_bf16.
// Grid (28 = 14bh x 2bw, 16n), 256 thr (4 waves). Block: 128k x 4h x 32w
// (bw=1 covers w32..55, sh1/si1 frag masked off -> ns {2,1}).
// Waves: (kp,sh) : 64k x 2 sfrags (4h x 8w).
// LDS: 2 phases x [6 rows][40 cols][8 oct-slots][16B], slot=(oct+col)&7
// (additive swizzle -> conflict-free b128 reads). Both phases staged in
// prologue (single barrier); 72-step K-loop with dist-1 A/B parity prefetch.
__global__ __launch_bounds__(256, 2) void conv_kernel(
    const float* __restrict__ x, const unsigned short* __restrict__ wt4,
    float* __restrict__ out) {
  __shared__ __align__(16) unsigned char xs[2 * PH_STRIDE];  // 75 KB

  const int tid = threadIdx.x;
  const int lane = tid & 63;
  const int wv = tid >> 6;    // 0..3
  const int bx = blockIdx.x;  // 0..27
  const int bh = bx >> 1;
  const int bw = bx & 1;
  const int n = blockIdx.y;
  const int r0 = bh * 4;

  const int p = lane & 31;
  const int dr = p >> 3;     // 0..3
  const int dw = p & 7;      // 0..7
  const int hi = lane >> 5;  // 0..1

  const int kp = wv >> 1;
  const int sh = wv & 1;
  const int ns = (bw & sh) ? 1 : 2;

  // ---- prologue: stage BOTH 64-ch phases (fp32 -> bf16 -> LDS) ----
  // lane = local col (0..33 active); input col = bw*32 + lane - 1.
  {
    const int scol = bw * 32 + lane - 1;
    const bool cok = (lane < 34) && (scol >= 0) && (scol < WW);
#pragma unroll
    for (int ph = 0; ph < 2; ++ph) {
#pragma unroll
      for (int o2 = 0; o2 < 2; ++o2) {
        const int o = wv * 2 + o2;  // oct 0..7
        const float* xb = x + ((size_t)n * CC + ph * 64 + o * 8) * HW + scol;
#pragma unroll
        for (int lr = 0; lr < 6; ++lr) {
          const int gh = r0 - 1 + lr;
          const bool ok = cok && (gh >= 0) && (gh < HH);
          const float* xpp = xb + gh * WW;
          float v0 = ok ? xpp[0 * HW] : 0.f;
          float v1 = ok ? xpp[1 * HW] : 0.f;
          float v2 = ok ? xpp[2 * HW] : 0.f;
          float v3 = ok ? xpp[3 * HW] : 0.f;
          float v4 = ok ? xpp[4 * HW] : 0.f;
          float v5 = ok ? xpp[5 * HW] : 0.f;
          float v6 = ok ? xpp[6 * HW] : 0.f;
          float v7 = ok ? xpp[7 * HW] : 0.f;
          if (lane < 34) {
            unsigned int q0 = (unsigned int)f2bf(v0) | ((unsigned int)f2bf(v1) << 16);
            unsigned int q1 = (unsigned int)f2bf(v2) | ((unsigned int)f2bf(v3) << 16);
            unsigned int q2 = (unsigned int)f2bf(v4) | ((unsigned int)f2bf(v5) << 16);
            unsigned int q3 = (unsigned int)f2bf(v6) | ((unsigned int)f2bf(v7) << 16);
            u32x4 qq = {q0, q1, q2, q3};
            const int a16 = (lr * 40 + lane) * 8 + ((o + lane) & 7);
            *(u32x4*)(xs + ph * PH_STRIDE + a16 * 16) = qq;
          }
        }
      }
    }
  }
  __syncthreads();

  // ---- 72-step K-loop (2 ph x 9 rs x 4 cs), dist-1 parity prefetch ----
  const int Vbase = (dr * 40 + sh * 16 + dw) * 128;  // byte base in phase
  const int T = sh * 16 + dw + hi;                   // slot source

  f32x16 acc[2][2] = {};   // [kfl][si]
  bf16x8 Ar[2][2], Br[2][2];

  auto ldstep = [&](int t, int pr) {
    const int ph = t / 36;
    const int st = t - ph * 36;        // rs*4 + cs
    const int rs = st >> 2;
    const int cs = st & 3;
    const int fr = (rs * 11) >> 5;     // rs/3
    const int fs = rs - fr * 3;
    const int ae = (((ph * 36 + st) * 4 + kp * 2) << 9) + lane * 8;
    Ar[pr][0] = *(const bf16x8*)(wt4 + ae);
    Ar[pr][1] = *(const bf16x8*)(wt4 + ae + 512);
    const int su = (T + fs + 2 * cs) & 7;
    const int bb = ph * PH_STRIDE + Vbase + (fr * 40 + fs) * 128 + su * 16;
    Br[pr][0] = *(const bf16x8*)(xs + bb);
    if (ns > 1) Br[pr][1] = *(const bf16x8*)(xs + bb + 8 * 128);
  };

  ldstep(0, 0);
#pragma unroll
  for (int t = 0; t < 72; ++t) {
    if (t < 71) ldstep(t + 1, (t + 1) & 1);
    bf16x8* A = Ar[t & 1];
    bf16x8* B = Br[t & 1];
    acc[0][0] = mfma32(A[0], B[0], acc[0][0]);
    acc[1][0] = mfma32(A[1], B[0], acc[1][0]);
    if (ns > 1) {
      acc[0][1] = mfma32(A[0], B[1], acc[0][1]);
      acc[1][1] = mfma32(A[1], B[1], acc[1][1]);
    }
  }

  // ---- epilogue: C/D col=lane&31 -> spatial; k=(r&3)+8*(r>>2)+4*hi ----
  const int ow0 = bw * 32 + sh * 16 + dw;
#pragma unroll
  for (int kfl = 0; kfl < 2; ++kfl) {
#pragma unroll
    for (int si = 0; si < 2; ++si) {
      if (si < ns) {
        float* op = out + (((size_t)n * KK + kp * 64 + kfl * 32 + (hi << 2)) * HH +
                           (r0 + dr)) * WW + ow0 + si * 8;
#pragma unroll
        for (int r = 0; r < 16; ++r) {
          const int ko = (r & 3) + ((r >> 2) << 3);
          op[(size_t)ko * HW] = acc[kfl][si][r];
        }
      }
    }
  }
}

extern "C" void kernel_launch(void* const* d_in, const int* in_sizes, int n_in,
                              void* d_out, int out_size, void* d_ws, size_t ws_size,
                              hipStream_t stream) {
  const float* x = (const float*)d_in[0];
  const float* kin = (const float*)d_in[1];
  float* out = (float*)d_out;
  unsigned short* wt4 = (unsigned short*)d_ws;  // 288 KB

  hipLaunchKernelGGL(wtrans_kernel, dim3(576), dim3(256), 0, stream, kin, wt4);
  hipLaunchKernelGGL(conv_kernel, dim3(28, 16), dim3(256), 0, stream, x, wt4, out);
}

// Round 6
// 40.638 us; speedup vs baseline: 1.3214x; 1.3214x over previous
//
#include <hip/hip_runtime.h>
#include <hip/hip_bf16.h>

typedef __attribute__((ext_vector_type(8))) short bf16x8;
typedef __attribute__((ext_vector_type(4))) float f32x4;
typedef __attribute__((ext_vector_type(4))) unsigned int u32x4;

#define CC 128
#define KK 128
#define HH 56
#define WW 56
#define HW (HH * WW)

#define XPH 43520                      // x LDS bytes per 64-ch phase: 10*34*128
#define ABASE (2 * XPH)                // 87040
#define CHUNK 16384                    // A chunk: [c2][f(8)][lane(64)][16B]
#define LDS_TOTAL (ABASE + 2 * CHUNK)  // 119808

__device__ __forceinline__ unsigned short f2bf(float f) {
  unsigned int u = __builtin_bit_cast(unsigned int, f);
  u += 0x7FFFu + ((u >> 16) & 1u);
  return (unsigned short)(u >> 16);
}

__device__ __forceinline__ void gload_lds16(const void* g, void* l) {
  __builtin_amdgcn_global_load_lds((__attribute__((address_space(1))) void*)g,
                                   (__attribute__((address_space(3))) void*)l,
                                   16, 0, 0);
}

// K1: kernel (K,C,3,3) f32 -> wt5 bf16 in A-fragment chunk order.
// e = ((((ph*9+rs)*2 + c2)*8 + f)*64 + l)*8 + j
// k = f*16 + (l&15) ; c = ph*64 + c2*32 + (l>>4)*8 + j
__global__ void wtrans_kernel(const float* __restrict__ kin,
                              unsigned short* __restrict__ wt5) {
  int e = blockIdx.x * 256 + threadIdx.x;  // 147456 exact
  int j = e & 7;
  int l = (e >> 3) & 63;
  int f = (e >> 9) & 7;
  int c2 = (e >> 12) & 1;
  int g = e >> 13;  // ph*9+rs, 0..17
  int ph = (g >= 9) ? 1 : 0;
  int rs = g - ph * 9;
  int k = f * 16 + (l & 15);
  int c = ph * 64 + c2 * 32 + (l >> 4) * 8 + j;
  wt5[e] = f2bf(kin[(k * CC + c) * 9 + rs]);
}

// K2: 3x3 conv, implicit GEMM, mfma_f32_16x16x32_bf16.
// Grid (14 = 7bh x 2bw, 16n), 512 thr (8 waves). Block tile: 128k x 8h x 32w.
// Wave (kp, hp): 64k x (2h x 32w) = 4x4 frags of 16x16. bw=1 -> 24w (ns=3).
// LDS: x[2ph][10r][34c][8 slots][16B] swizzled slot=oct^(col&7), staged once
// in prologue; A ring-2 chunks (16KB per (ph,rs)) via global_load_lds with
// counted vmcnt(2) + raw barrier pair per chunk.
__global__ __launch_bounds__(512, 2) void conv_kernel(
    const float* __restrict__ x, const unsigned short* __restrict__ wt5,
    float* __restrict__ out) {
  __shared__ __align__(16) unsigned char xs[LDS_TOTAL];

  const int tid = threadIdx.x;
  const int lane = tid & 63;
  const int wv = tid >> 6;    // 0..7
  const int bh = blockIdx.x >> 1;  // 0..6
  const int bw = blockIdx.x & 1;
  const int n = blockIdx.y;
  const int r0 = bh * 8;

  const int cidx = lane & 15;  // spatial col within fragment
  const int dh = cidx >> 3;    // 0..1
  const int dwf = cidx & 7;    // 0..7
  const int q = lane >> 4;     // 0..3 (k/ch slice)

  const int hp = wv & 3;   // h-pair 0..3
  const int kp = wv >> 2;  // k-half 0..1
  const int ns = bw ? 3 : 4;

  const unsigned char* wt5b = (const unsigned char*)wt5;

  // issue A chunk 0 -> ring slot 0 (2 wave-instrs of 1KB per wave)
#pragma unroll
  for (int i = 0; i < 2; ++i) {
    const int off = (wv * 2 + i) * 1024;
    gload_lds16(wt5b + off + lane * 16, xs + ABASE + off);
  }

  // ---- stage x, both 64-ch phases: fp32 -> bf16 -> LDS ----
#pragma unroll
  for (int ph = 0; ph < 2; ++ph) {
#pragma unroll
    for (int i = 0; i < 6; ++i) {
      int idx = tid + 512 * i;  // cell = (o, row, col), col fastest
      if (idx < 2720) {
        int col = idx % 34;
        int t2 = idx / 34;
        int row = t2 % 10;
        int o = t2 / 10;
        int gr = r0 - 1 + row;
        int gc = bw * 32 - 1 + col;
        bool ok = (gr >= 0) && (gr < HH) && (gc >= 0) && (gc < WW);
        const float* sp =
            x + ((size_t)(n * CC + ph * 64 + o * 8)) * HW + gr * WW + gc;
        float v0 = ok ? sp[0 * HW] : 0.f;
        float v1 = ok ? sp[1 * HW] : 0.f;
        float v2 = ok ? sp[2 * HW] : 0.f;
        float v3 = ok ? sp[3 * HW] : 0.f;
        float v4 = ok ? sp[4 * HW] : 0.f;
        float v5 = ok ? sp[5 * HW] : 0.f;
        float v6 = ok ? sp[6 * HW] : 0.f;
        float v7 = ok ? sp[7 * HW] : 0.f;
        unsigned int p0 = (unsigned int)f2bf(v0) | ((unsigned int)f2bf(v1) << 16);
        unsigned int p1 = (unsigned int)f2bf(v2) | ((unsigned int)f2bf(v3) << 16);
        unsigned int p2 = (unsigned int)f2bf(v4) | ((unsigned int)f2bf(v5) << 16);
        unsigned int p3 = (unsigned int)f2bf(v6) | ((unsigned int)f2bf(v7) << 16);
        u32x4 qq = {p0, p1, p2, p3};
        *(u32x4*)(xs + ph * XPH + (row * 34 + col) * 128 +
                  ((o ^ (col & 7)) << 4)) = qq;
      }
    }
  }
  __syncthreads();  // x staged; chunk0 also drained here

  f32x4 acc[4][4] = {};  // [f][si]

#pragma unroll 1
  for (int ct = 0; ct < 18; ++ct) {
    // issue next A chunk (re-issues 17 on last iter to keep vmcnt uniform)
    const int cn = (ct < 17) ? ct + 1 : 17;
    const unsigned char* srcb = wt5b + cn * CHUNK;
    unsigned char* dstb = xs + ABASE + ((ct + 1) & 1) * CHUNK;
#pragma unroll
    for (int i = 0; i < 2; ++i) {
      const int off = (wv * 2 + i) * 1024;
      gload_lds16(srcb + off + lane * 16, dstb + off);
    }
    asm volatile("s_waitcnt vmcnt(2)" ::: "memory");  // chunk ct landed
    __builtin_amdgcn_s_barrier();
    asm volatile("" ::: "memory");

    const int ph = (ct >= 9) ? 1 : 0;
    const int rs = ct - ph * 9;
    const int fr = (rs * 11) >> 5;  // rs/3
    const int fs = rs - fr * 3;
    const int rowb = hp * 2 + dh + fr;
    const int colb = dwf + fs;  // per-lane; col_l = si*8 + colb
    const unsigned char* bb = xs + ph * XPH + (rowb * 34 + colb) * 128;
    const unsigned char* ab = xs + ABASE + (ct & 1) * CHUNK + lane * 16;

#pragma unroll
    for (int c2 = 0; c2 < 2; ++c2) {
      bf16x8 A[4], B[4];
#pragma unroll
      for (int f = 0; f < 4; ++f)
        A[f] = *(const bf16x8*)(ab + (c2 * 8 + kp * 4 + f) * 1024);
      const int sl = ((c2 * 4 + q) ^ (colb & 7)) << 4;
#pragma unroll
      for (int si = 0; si < 4; ++si)
        if (si < ns) B[si] = *(const bf16x8*)(bb + si * 1024 + sl);
#pragma unroll
      for (int f = 0; f < 4; ++f)
#pragma unroll
        for (int si = 0; si < 4; ++si)
          if (si < ns)
            acc[f][si] = __builtin_amdgcn_mfma_f32_16x16x32_bf16(
                A[f], B[si], acc[f][si], 0, 0, 0);
    }
    asm volatile("" ::: "memory");
    __builtin_amdgcn_s_barrier();  // all waves done reading slot ct&1
  }

  // ---- epilogue: C/D 16x16: col=lane&15 -> spatial, row=(lane>>4)*4+j -> k
  const int h = r0 + hp * 2 + dh;
#pragma unroll
  for (int f = 0; f < 4; ++f) {
#pragma unroll
    for (int si = 0; si < 4; ++si) {
      if (si < ns) {
        const int k = kp * 64 + f * 16 + q * 4;
        const int w = bw * 32 + si * 8 + dwf;
        float* op = out + (((size_t)n * KK + k) * HH + h) * WW + w;
#pragma unroll
        for (int j = 0; j < 4; ++j) op[(size_t)j * HW] = acc[f][si][j];
      }
    }
  }
}

extern "C" void kernel_launch(void* const* d_in, const int* in_sizes, int n_in,
                              void* d_out, int out_size, void* d_ws, size_t ws_size,
                              hipStream_t stream) {
  const float* x = (const float*)d_in[0];
  const float* kin = (const float*)d_in[1];
  float* out = (float*)d_out;
  unsigned short* wt5 = (unsigned short*)d_ws;  // 288 KB

  hipLaunchKernelGGL(wtrans_kernel, dim3(576), dim3(256), 0, stream, kin, wt5);
  hipLaunchKernelGGL(conv_kernel, dim3(14, 16), dim3(512), 0, stream, x, wt5, out);
}